// Round 4
// baseline (238.884 us; speedup 1.0000x reference)
//
#include <hip/hip_runtime.h>
#include <hip/hip_bf16.h>
#include <math.h>

// inp [B=16, S=4096, D=512] fp32, lengths [16] int32.
// out [B, S, 513] fp32: out[...,0:512] = inp, out[...,512] = pe(b,s).
//
// Register-only shift, no LDS, no barrier:
//  - Block = 256 threads handles 16 rows. 16 out rows = 32,832 B = exactly 513
//    cache lines -> blocks own whole lines; base % 16 == 0 -> every float4
//    store aligned; dense & coalesced.
//  - Out f4 at block-local dword q (row r=q/513) needs input dwords
//    q-r..q+3-r: covered by two ADJACENT aligned input float4s (A,B).
//    Lane-consecutive A-loads are perfectly coalesced; B is lane i+1's A
//    (L1 hit). Rotation window s_k = win[off+k], off=(q-r)&3, via 3 cmps +
//    12 cndmasks (masks reused across components).
//  - Exactly one f4 per row contains col 512 (c>508): insert pe at kpe=512-c;
//    components after it are next-row values = s_{k-1} (same window, free).

#define PB 16
#define PS 4096
#define PD 512
#define RPB 16                          // rows per block
#define OUT_F4_BLK (RPB * (PD + 1) / 4) // 2052
#define IN_F4_BLK  (RPB * PD / 4)       // 2048
#define NBLOCKS ((PB * PS) / RPB)       // 4096
#define MAX_IN_F4 (PB * PS * PD / 4)    // 8,388,608
#define PI_F 3.14159265358979323846f

__global__ __launch_bounds__(256) void sinpe_kernel(
    const float4* __restrict__ in4,
    const int* __restrict__ lengths,
    float4* __restrict__ out4)
{
    const int blk = blockIdx.x;
    const int t   = threadIdx.x;

    const float4* __restrict__ inb  = in4  + (size_t)blk * IN_F4_BLK;
    float4* __restrict__       outb = out4 + (size_t)blk * OUT_F4_BLK;
    // clamp for the one OOB-by-16B neighbor load of the very last block
    // (its value is never used there; only the address must be in-bounds)
    const int last_in = (MAX_IN_F4 - 1) - blk * IN_F4_BLK;

    #pragma unroll
    for (int j = 0; j < 9; ++j) {
        const int o = j * 256 + t;              // out f4 within block
        if (o < OUT_F4_BLK) {                   // j==8: only t<4 active
            const unsigned q = 4u * (unsigned)o;    // out dword within block
            const unsigned r = q / 513u;            // local row 0..15 (magic mul)
            const unsigned c = q - 513u * r;        // col 0..512
            const int wd  = (int)(q - r);           // first needed in-dword
            const int ia  = wd >> 2;
            int ib = ia + 1; if (ib > last_in) ib = last_in;
            const float4 A = inb[ia];
            const float4 B = inb[ib];
            const int off = wd & 3;

            const bool o1 = (off == 1), o2 = (off == 2), o3 = (off == 3);
            // s_k = input dword (q - r + k)
            float s0 = o1 ? A.y : (o2 ? A.z : (o3 ? A.w : A.x));
            float s1 = o1 ? A.z : (o2 ? A.w : (o3 ? B.x : A.y));
            float s2 = o1 ? A.w : (o2 ? B.x : (o3 ? B.y : A.z));
            float s3 = o1 ? B.x : (o2 ? B.y : (o3 ? B.z : A.w));

            float4 v;
            if (c <= 508u) {
                // fast path: pure copy, cols c..c+3 of row r
                v.x = s0; v.y = s1; v.z = s2; v.w = s3;
            } else {
                // slow path: insert pe at kpe; k>kpe are next-row = s_{k-1}
                const int kpe  = 512 - (int)c;       // 0..3
                const int rowg = blk * RPB + (int)r;
                const int s    = rowg & (PS - 1);
                const int b    = rowg >> 12;
                const int len  = lengths[b];
                float pe = 0.0f;
                if (s < len) {
                    pe = cosf(((float)s / fmaxf((float)len, 1.0f)) * PI_F);
                }
                v.x = (kpe == 0) ? pe : s0;
                v.y = (kpe == 1) ? pe : ((kpe == 0) ? s0 : s1);
                v.z = (kpe == 2) ? pe : ((kpe == 3) ? s2 : s1);
                v.w = (kpe == 3) ? pe : s2;
            }
            outb[o] = v;   // 16B-aligned, dense, block owns whole 64B lines
        }
    }
}

extern "C" void kernel_launch(void* const* d_in, const int* in_sizes, int n_in,
                              void* d_out, int out_size, void* d_ws, size_t ws_size,
                              hipStream_t stream)
{
    const float4* in4     = (const float4*)d_in[0];
    const int*    lengths = (const int*)d_in[1];
    float4*       out4    = (float4*)d_out;

    sinpe_kernel<<<NBLOCKS, 256, 0, stream>>>(in4, lengths, out4);
}